// Round 13
// baseline (168.635 us; speedup 1.0000x reference)
//
#include <hip/hip_runtime.h>
#include <math.h>

#define D_MODEL 1024
#define D_FF    4096
#define RANK    128
#define M_ROWS  8192

typedef _Float16 f16;
typedef _Float16 f16x8 __attribute__((ext_vector_type(8)));
typedef _Float16 f16x4 __attribute__((ext_vector_type(4)));
typedef float    f32x4 __attribute__((ext_vector_type(4)));

#define MFMA16(a, b, c) __builtin_amdgcn_mfma_f32_16x16x32_f16((a), (b), (c), 0, 0, 0)

__device__ __forceinline__ f16x8 ld8(const f16* p) { return *(const f16x8*)p; }

__device__ __forceinline__ f16x8 cvt8(float4 a0, float4 a1) {
    f16x8 r = { (f16)a0.x, (f16)a0.y, (f16)a0.z, (f16)a0.w,
                (f16)a1.x, (f16)a1.y, (f16)a1.z, (f16)a1.w };
    return r;
}

// Fast exact-gelu (proven R2/R4/R8, absmax 9.77e-4).
__device__ __forceinline__ float gelu_fast(float v) {
    float u  = v * 0.70710678118654752440f;
    float au = fabsf(u);
    float t  = __builtin_amdgcn_rcpf(__builtin_fmaf(0.3275911f, au, 1.0f));
    float e  = __expf(-au * au);
    float p  = __builtin_fmaf(1.061405429f, t, -1.453152027f);
    p = __builtin_fmaf(p, t, 1.421413741f);
    p = __builtin_fmaf(p, t, -0.284496736f);
    p = __builtin_fmaf(p, t, 0.254829592f);
    float er = __builtin_fmaf(-p * t, e, 1.0f);
    er = copysignf(er, u);
    return 0.5f * v * (1.0f + er);
}

// async global->LDS, 16 B per lane; LDS dest wave-uniform base + lane*16
#define GLOAD16(gp, lp) __builtin_amdgcn_global_load_lds(                     \
    (const __attribute__((address_space(1))) void*)(gp),                      \
    (__attribute__((address_space(3))) void*)(lp), 16, 0, 0)

// ---------------------------------------------------------------------------
// Prep (R1 set, kept).
// ---------------------------------------------------------------------------
__global__ __launch_bounds__(256) void k_prep(
    const float* __restrict__ cfcU, const float* __restrict__ cfcS,
    const float* __restrict__ cfcV, const float* __restrict__ pjU,
    const float* __restrict__ pjS,  const float* __restrict__ pjV,
    f16* __restrict__ w1T, f16* __restrict__ v1,
    f16* __restrict__ w2T, f16* __restrict__ v2)
{
    int i = blockIdx.x * 256 + threadIdx.x;
    if (i < 131072) {
        int r = i >> 10, d = i & 1023;
        w1T[i] = (f16)(cfcU[d * RANK + r] * cfcS[r]);
    } else if (i < 655360) {
        int j = i - 131072;
        v1[j] = (f16)cfcV[j];
    } else if (i < 1179648) {
        int j = i - 655360;
        int r = j >> 12, f = j & 4095;
        w2T[j] = (f16)(pjU[f * RANK + r] * pjS[r]);
    } else if (i < 1310720) {
        int j = i - 1179648;
        v2[j] = (f16)pjV[j];
    }
}

// ---------------------------------------------------------------------------
// Stage 1 (R1 set, kept): t1p[h][m][r] = x[m][K-half h] @ w1T^T.
// ---------------------------------------------------------------------------
__global__ __launch_bounds__(512, 2) void k_t1(
    const float* __restrict__ x, const f16* __restrict__ w1T,
    f16* __restrict__ t1p)
{
    __shared__ __align__(16) f16 w1s[128 * 520];   // 133120 B

    const int tid  = threadIdx.x;
    const int lane = tid & 63;
    const int wv   = tid >> 6;
    const int wm   = wv & 3, wn = wv >> 2;
    const int m0b  = blockIdx.x * 64;
    const int h    = blockIdx.y;
    const int c    = lane & 15, q = lane >> 4;

#define LOADX(dst, kc)                                                          \
    _Pragma("unroll") for (int kb = 0; kb < 4; ++kb) {                          \
        const float* px = &x[(size_t)(m0b + wm * 16 + c) * D_MODEL +            \
                             h * 512 + (kc) * 128 + kb * 32 + q * 8];           \
        dst[kb][0] = *(const float4*)px;                                        \
        dst[kb][1] = *(const float4*)(px + 4); }

#define COMPUTEKC(src, kc)                                                      \
    _Pragma("unroll") for (int kb = 0; kb < 4; ++kb) {                          \
        f16x8 af = cvt8(src[kb][0], src[kb][1]);                                \
        _Pragma("unroll") for (int nt = 0; nt < 4; ++nt) {                      \
            f16x8 bf = *(const f16x8*)                                          \
                &w1s[(wn * 64 + nt * 16 + c) * 520 + (kc) * 128 + kb * 32 + q * 8]; \
            acc[nt] = MFMA16(af, bf, acc[nt]); } }

    float4 xa[4][2], xb[4][2];
    LOADX(xa, 0)

#pragma unroll
    for (int i = 0; i < 16; ++i) {
        int id = i * 512 + tid;
        int rr = id >> 6, k8 = id & 63;
        *(f16x8*)&w1s[rr * 520 + k8 * 8] =
            ld8(w1T + (size_t)rr * D_MODEL + h * 512 + k8 * 8);
    }
    __syncthreads();

    f32x4 acc[4] = {};
    LOADX(xb, 1)
    COMPUTEKC(xa, 0)
    LOADX(xa, 2)
    COMPUTEKC(xb, 1)
    LOADX(xb, 3)
    COMPUTEKC(xa, 2)
    COMPUTEKC(xb, 3)

    f16* o = t1p + (size_t)h * (M_ROWS * RANK);
#pragma unroll
    for (int nt = 0; nt < 4; ++nt)
#pragma unroll
        for (int i2 = 0; i2 < 4; ++i2)
            o[(size_t)(m0b + wm * 16 + q * 4 + i2) * RANK + wn * 64 + nt * 16 + c] =
                (f16)acc[nt][i2];
#undef LOADX
#undef COMPUTEKC
}

// ---------------------------------------------------------------------------
// Fused stages 2+3 v10: v8r + CROSS-ITERATION S3 PIPELINE (T15 idea).
// R12 diagnosis: per-iter chain S2->gelu->drain->S3->barrier is serial; both
// pipes idle (Mfma 12.5%, VALU 43% @ 2 waves/SIMD). v10: in iter it, issue
// S3(it-1) FIRST (operands ready: hs[prev] from last gelu, w2s tile it-1);
// its 8 MFMAs accumulate independent c3[rt] consumed next iter -> no wait;
// gelu(it) VALU then runs UNDER S3's MFMA latency. hs 2-deep (+7 KB, LDS
// 79872 <= 80K -> still 2 blocks/CU). Barrier A protects w2s[(it-1)&1]
// (read by S3) from STAGE(it+1)'s overwrite of the same buffer; cheap (no
// vmcnt pending there). Barrier B (iter end) = v8's landing barrier.
// ---------------------------------------------------------------------------
#define V1OFF 0          // [2][64 f][256 B]   32768
#define W2OFF 32768      // [2][128 r][128 B]  32768
#define HSOFF 65536      // [2 deep][4 waves][16 m][56 f16]  14336  -> 79872
#define HSTR  56

__global__ __launch_bounds__(256, 2) void k_fused(
    const f16* __restrict__ t1p, const f16* __restrict__ v1,
    const float* __restrict__ bfc, const f16* __restrict__ w2T,
    f16* __restrict__ t2p)
{
    __shared__ __align__(16) char smem[79872];

    const int tid  = threadIdx.x;
    const int lane = tid & 63;
    const int wv   = tid >> 6;                     // 0..3
    const int wm   = wv & 1, wf = wv >> 1;
    const int c    = lane & 15, q = lane >> 4;

    // XCD swizzle (bijective, 512 = 64*8): XCDs 0-3 -> s=0, 4-7 -> s=1
    const int bx  = blockIdx.x;
    const int s   = (bx & 7) >> 2;
    const int mb  = (bx >> 3) * 4 + (bx & 3);      // 0..255
    const int m0b = mb * 32;
    const int fw  = wf * 32;                       // wave's f-slice in 64-f tile

    f16* hs0 = (f16*)(smem + HSOFF + wv * 1792);          // [16][56]
    f16* hs1 = (f16*)(smem + HSOFF + 7168 + wv * 1792);

#define STAGE(bsel, itn) {                                                      \
    const int ft_ = s * 2048 + (itn) * 64;                                      \
    _Pragma("unroll") for (int i = 0; i < 4; ++i) {                             \
        int rb_  = wv * 16 + i * 4;                                             \
        int row_ = rb_ + (lane >> 4);                                           \
        int col_ = ((lane & 15) * 16) ^ ((row_ & 15) << 4);                     \
        GLOAD16((const char*)v1 + (size_t)(ft_ + row_) * 256 + col_,            \
                smem + V1OFF + (bsel) * 16384 + rb_ * 256);                     \
    }                                                                           \
    _Pragma("unroll") for (int i = 0; i < 4; ++i) {                             \
        int rb_  = wv * 32 + i * 8;                                             \
        int row_ = rb_ + (lane >> 3);                                           \
        int col_ = ((lane & 7) * 16) ^ ((row_ & 7) << 4);                       \
        GLOAD16((const char*)w2T + (size_t)row_ * 8192 + (size_t)ft_ * 2 + col_,\
                smem + W2OFF + (bsel) * 16384 + rb_ * 128);                     \
    }                                                                           \
}

    // S3: c3 += h(prev iter) @ w2T^T, tile buffer bsel
#define S3STEP(hsrc, bsel) {                                                    \
    f16x8 a3 = *(const f16x8*)((hsrc) + c * HSTR + q * 8);                      \
    _Pragma("unroll") for (int rt = 0; rt < 8; ++rt) {                          \
        int rr = rt * 16 + c;                                                   \
        f16x8 bw = *(const f16x8*)(smem + W2OFF + (bsel) * 16384 +              \
            rr * 128 + ((wf * 64 + q * 16) ^ ((c & 7) << 4)));                  \
        c3[rt] = MFMA16(a3, bw, c3[rt]);                                        \
    }                                                                           \
}

    // A2 fragments: f16 sum of the two t1 partials (proven)
    f16x8 a2[4];
#pragma unroll
    for (int kb = 0; kb < 4; ++kb) {
        const size_t off = (size_t)(m0b + wm * 16 + c) * RANK + kb * 32 + q * 8;
        f16x8 p0 = ld8(t1p + off);
        f16x8 p1 = ld8(t1p + (size_t)(M_ROWS * RANK) + off);
#pragma unroll
        for (int e = 0; e < 8; ++e)
            a2[kb][e] = (f16)((float)p0[e] + (float)p1[e]);
    }

    STAGE(0, 0)
    __syncthreads();                               // buf0 landed (vmcnt drain)

    f32x4 c3[8] = {};

#pragma unroll 1
    for (int it = 0; it < 32; ++it) {
        const int cur = it & 1;
        const int ft  = s * 2048 + it * 64;
        f16* hcur  = cur ? hs1 : hs0;
        f16* hprev = cur ? hs0 : hs1;

        // ---- S3(it-1): operands ready; independent accumulates, no wait
        if (it > 0) S3STEP(hprev, cur ^ 1)

        __syncthreads();   // A: all waves' S3 reads of buf cur^1 done (cheap:
                           //    no vmcnt pending — prev STAGE drained at B)

        float bb[2];
        bb[0] = bfc[ft + fw + c];
        bb[1] = bfc[ft + fw + 16 + c];

        if (it < 31) STAGE(cur ^ 1, it + 1)        // overwrite freed buffer

        // ---- stage 2: h[16m][32f] = t1 @ v1^T (2 nt x 4 kb MFMA)
        f32x4 c2[2] = {};
#pragma unroll
        for (int nt = 0; nt < 2; ++nt)
#pragma unroll
            for (int kb = 0; kb < 4; ++kb) {
                int row = fw + nt * 16 + c;
                f16x8 bv = *(const f16x8*)(smem + V1OFF + cur * 16384 +
                    row * 256 + ((kb * 64 + q * 16) ^ ((row & 15) << 4)));
                c2[nt] = MFMA16(a2[kb], bv, c2[nt]);
            }

        // ---- bias + gelu -> hs[cur] (runs under S3's MFMA latency)
#pragma unroll
        for (int nt = 0; nt < 2; ++nt)
#pragma unroll
            for (int i2 = 0; i2 < 4; ++i2)
                hcur[(q * 4 + i2) * HSTR + nt * 16 + c] =
                    (f16)gelu_fast(c2[nt][i2] + bb[nt]);
        asm volatile("s_waitcnt lgkmcnt(0)" ::: "memory"); // wave-local RAW

        __syncthreads();   // B: STAGE(it+1) landed; iteration boundary
    }

    // ---- drain: S3(31) (hs of iter 31 = hs1, tile 31 in buf 1)
    S3STEP(hs1, 1)
#undef STAGE
#undef S3STEP

    // ---- epilogue: 2-wave reduce over wf (proven), write f16 t2p[s]
    __syncthreads();
    float* rbuf = (float*)smem;

    if (wf == 1) {
        float* rb = rbuf + wm * 2112;
#pragma unroll
        for (int rt = 0; rt < 8; ++rt)
#pragma unroll
            for (int i2 = 0; i2 < 4; ++i2)
                rb[(q * 4 + i2) * 132 + rt * 16 + c] = c3[rt][i2];
    }
    __syncthreads();
    if (wf == 0) {
        float* rb = rbuf + wm * 2112;
#pragma unroll
        for (int rt = 0; rt < 8; ++rt)
#pragma unroll
            for (int i2 = 0; i2 < 4; ++i2)
                c3[rt][i2] += rb[(q * 4 + i2) * 132 + rt * 16 + c];
        f16* o = t2p + (size_t)s * (M_ROWS * RANK);
#pragma unroll
        for (int rt = 0; rt < 8; ++rt)
#pragma unroll
            for (int i2 = 0; i2 < 4; ++i2)
                o[(size_t)(m0b + wm * 16 + q * 4 + i2) * RANK + rt * 16 + c] =
                    (f16)c3[rt][i2];
    }
}

// ---------------------------------------------------------------------------
// Stage 4 (R1 set, kept): out = (t2p0+t2p1) @ v2^T + bpj.
// ---------------------------------------------------------------------------
__global__ __launch_bounds__(256, 2) void k_out(
    const f16* __restrict__ t2p, const f16* __restrict__ v2,
    const float* __restrict__ bpj, float* __restrict__ out)
{
    __shared__ __align__(16) f16 v2s[256 * 136];

    const int tid  = threadIdx.x;
    const int lane = tid & 63;
    const int wv   = tid >> 6;
    const int wm   = wv & 1, wn = wv >> 1;
    const int m0b  = blockIdx.x * 32;
    const int n0b  = blockIdx.y * 256;
    const int c    = lane & 15, q = lane >> 4;

#pragma unroll
    for (int i8 = 0; i8 < 16; ++i8) {
        int id = i8 * 256 + tid;
        int nn = id >> 4, k8 = id & 15;
        *(f16x8*)&v2s[nn * 136 + k8 * 8] =
            ld8(v2 + (size_t)(n0b + nn) * RANK + k8 * 8);
    }

    f16x8 a[4];
#pragma unroll
    for (int kb = 0; kb < 4; ++kb) {
        const size_t off = (size_t)(m0b + wm * 16 + c) * RANK + kb * 32 + q * 8;
        f16x8 p0 = ld8(t2p + off);
        f16x8 p1 = ld8(t2p + (size_t)(M_ROWS * RANK) + off);
#pragma unroll
        for (int e = 0; e < 8; ++e)
            a[kb][e] = (f16)((float)p0[e] + (float)p1[e]);
    }
    __syncthreads();

    f32x4 acc[8] = {};
#pragma unroll
    for (int nt = 0; nt < 8; ++nt)
#pragma unroll
        for (int kb = 0; kb < 4; ++kb) {
            f16x8 bf = *(const f16x8*)
                &v2s[(wn * 128 + nt * 16 + c) * 136 + kb * 32 + q * 8];
            acc[nt] = MFMA16(a[kb], bf, acc[nt]);
        }

#pragma unroll
    for (int nt = 0; nt < 8; ++nt) {
        float b = bpj[n0b + wn * 128 + nt * 16 + c];
#pragma unroll
        for (int i2 = 0; i2 < 4; ++i2)
            out[(size_t)(m0b + wm * 16 + q * 4 + i2) * D_MODEL +
                n0b + wn * 128 + nt * 16 + c] = acc[nt][i2] + b;
    }
}

extern "C" void kernel_launch(void* const* d_in, const int* in_sizes, int n_in,
                              void* d_out, int out_size, void* d_ws, size_t ws_size,
                              hipStream_t stream) {
    const float* x    = (const float*)d_in[0];
    const float* cfcU = (const float*)d_in[1];
    const float* cfcS = (const float*)d_in[2];
    const float* cfcV = (const float*)d_in[3];
    const float* cfcB = (const float*)d_in[4];
    const float* pjU  = (const float*)d_in[5];
    const float* pjS  = (const float*)d_in[6];
    const float* pjV  = (const float*)d_in[7];
    const float* pjB  = (const float*)d_in[8];
    float* out = (float*)d_out;

    // ws layout (f16 elements), 10.5 MB (12 MB proven safe):
    f16* wsf = (f16*)d_ws;
    f16* t1p = wsf;                 // [2][8192*128]  4 MB
    f16* t2p = wsf + 2097152;       // [2][8192*128]  4 MB
    f16* w1T = wsf + 4194304;       // [128*1024]
    f16* v1  = w1T + 131072;        // [4096*128]
    f16* w2T = v1  + 524288;        // [128*4096]
    f16* v2  = w2T + 524288;        // [1024*128]

    k_prep <<<dim3(5120), 256, 0, stream>>>(cfcU, cfcS, cfcV, pjU, pjS, pjV,
                                            w1T, v1, w2T, v2);
    k_t1   <<<dim3(M_ROWS / 64, 2), 512, 0, stream>>>(x, w1T, t1p);
    k_fused<<<dim3(512), 256, 0, stream>>>(t1p, v1, cfcB, w2T, t2p);
    k_out  <<<dim3(M_ROWS / 32, D_MODEL / 256), 256, 0, stream>>>(t2p, v2, pjB, out);
}